// Round 2
// 461.772 us; speedup vs baseline: 1.0355x; 1.0355x over previous
//
#include <hip/hip_runtime.h>

#define B 32
#define D 1024
#define UD 256
#define ENT 32
#define NENT 64
#define S 2048
#define C 65
#define NSLAB 8
#define SROWS 256   // S / NSLAB rows per fused block = 8 entities

__device__ __forceinline__ float dot4(float4 w, const float* q) {
    return w.x * q[0] + w.y * q[1] + w.z * q[2] + w.w * q[3];
}

// grid (20, 8): x = 64-row group of [W_unit; W_chunk] (1280 rows), y = 4-batch group.
__global__ __launch_bounds__(256) void k_proj(const float* __restrict__ src,
                                              const float* __restrict__ Wu,
                                              const float* __restrict__ Wc,
                                              float* __restrict__ qu,
                                              float* __restrict__ qc) {
    __shared__ alignas(16) float s_src[4][D];       // 16 KB
    __shared__ float red[4][64][4];                 // 4 KB
    int t = threadIdx.x, rg = blockIdx.x, bg = blockIdx.y;
    for (int f = t; f < 4 * (D / 4); f += 256) {
        int bb = f >> 8, i4 = f & 255;
        float4 v = *(const float4*)(src + (size_t)(bg * 4 + bb) * D + i4 * 4);
        *(float4*)(&s_src[bb][i4 * 4]) = v;
    }
    __syncthreads();
    int jl = t & 63, kq = t >> 6;
    int gj = rg * 64 + jl;
    const float* wrow = (gj < UD) ? (Wu + (size_t)gj * D) : (Wc + (size_t)(gj - UD) * D);
    const float4* wp = (const float4*)wrow + kq * 64;   // 64 float4 = 256 k
    float acc[4] = {0.f, 0.f, 0.f, 0.f};
#pragma unroll 4
    for (int i = 0; i < 64; ++i) {
        float4 w = wp[i];
        int k = kq * 256 + i * 4;
#pragma unroll
        for (int bb = 0; bb < 4; ++bb) acc[bb] += dot4(w, &s_src[bb][k]);
    }
#pragma unroll
    for (int bb = 0; bb < 4; ++bb) red[kq][jl][bb] = acc[bb];
    __syncthreads();
    {
        int jl2 = t & 63, bb = t >> 6;
        float s = red[0][jl2][bb] + red[1][jl2][bb] + red[2][jl2][bb] + red[3][jl2][bb];
        int gj2 = rg * 64 + jl2, b = bg * 4 + bb;
        if (gj2 < UD) qu[b * UD + gj2] = s;
        else qc[b * D + (gj2 - UD)] = s;
    }
}

// grid (C, B): raw chunk score sc[b*C+c] = qc[b] . hl[c,b]  (2080 blocks, latency-friendly)
__global__ __launch_bounds__(256) void k_score(const float* __restrict__ hl,
                                               const float* __restrict__ qc,
                                               float* __restrict__ sc) {
    __shared__ float red[4];
    int c = blockIdx.x, b = blockIdx.y, t = threadIdx.x;
    const float4* hp = (const float4*)(hl + ((size_t)c * B + b) * D);
    const float4* qp = (const float4*)(qc + (size_t)b * D);
    float4 h = hp[t];
    float4 q = qp[t];
    float acc = h.x * q.x + h.y * q.y + h.z * q.z + h.w * q.w;
    for (int o = 32; o >= 1; o >>= 1) acc += __shfl_xor(acc, o);
    if ((t & 63) == 0) red[t >> 6] = acc;
    __syncthreads();
    if (t == 0) sc[b * C + c] = red[0] + red[1] + red[2] + red[3];
}

// grid (NSLAB, B), 512 threads: fused unit scores + entity softmax + chunk softmax
// (redundant, cheap) + weighted context partial over this block's 256 s-rows.
// Two thread-halves each stream 128 ll rows; LDS-combined. 8 waves/CU for latency hiding.
__global__ __launch_bounds__(512) void k_fused(const float* __restrict__ pe,
                                               const float* __restrict__ ll,
                                               const int* __restrict__ lmask,
                                               const int* __restrict__ hmask,
                                               const float* __restrict__ qu,
                                               const float* __restrict__ sc,
                                               float* __restrict__ pf,
                                               float* __restrict__ out_au,
                                               float* __restrict__ out_ac,
                                               float* __restrict__ out_av) {
    __shared__ alignas(16) float q[UD];     // 1 KB
    __shared__ float s_ac[NENT];            // chunk attention (post-softmax, chunks 1..64)
    __shared__ float s_sc[SROWS];           // raw unit scores for this slab
    __shared__ float s_av[SROWS];           // final align_vectors for this slab
    __shared__ alignas(16) float4 s_red[256]; // 4 KB half-combine
    int ss = blockIdx.x, b = blockIdx.y, t = threadIdx.x;

    if (t < UD) q[t] = qu[b * UD + t];

    // ---- chunk masked softmax over 65 scores, wave 0 lanes 0..63 (redundant per block) ----
    if (t < 64) {
        bool m1 = hmask[b * C + t] != 0;
        float x1 = m1 ? -1e30f : sc[b * C + t];
        float x2 = -1e30f;
        bool m2 = true;
        if (t == 0) { m2 = hmask[b * C + 64] != 0; x2 = m2 ? -1e30f : sc[b * C + 64]; }
        float mx = fmaxf(x1, x2);
        for (int o = 32; o >= 1; o >>= 1) mx = fmaxf(mx, __shfl_xor(mx, o));
        float e1 = m1 ? 0.f : __expf(x1 - mx);
        float sm = e1 + ((t == 0 && !m2) ? __expf(x2 - mx) : 0.f);
        for (int o = 32; o >= 1; o >>= 1) sm += __shfl_xor(sm, o);
        // ac for chunk c = t+1 (drop chunk 0); maps to entity n = t
        bool mc = hmask[b * C + (t + 1)] != 0;
        float xc = mc ? 0.f : sc[b * C + (t + 1)];
        float p = mc ? 0.f : __expf(xc - mx) / sm;
        s_ac[t] = p;
        if (ss == 0) out_ac[b * NENT + t] = p;
    }
    __syncthreads();

    // ---- unit scores: 64 row-slots x 8 k-lanes, 4 passes -> 256 rows, coalesced float4 ----
    int rg = t >> 3, r = t & 7;
#pragma unroll
    for (int pass = 0; pass < 4; ++pass) {
        int j = pass * 64 + rg;             // local row in slab
        int s = ss * SROWS + j;
        const float4* pp = (const float4*)(pe + ((size_t)s * B + b) * UD) + r;
        float acc = 0.f;
#pragma unroll
        for (int i = 0; i < 8; ++i) {
            float4 v = pp[i * 8];           // lanes r=0..7 read consecutive float4s
            acc += dot4(v, &q[(r + i * 8) * 4]);
        }
        for (int o = 1; o < 8; o <<= 1) acc += __shfl_xor(acc, o);
        if (r == 0) s_sc[j] = acc;
    }
    __syncthreads();

    // ---- entity masked softmax (8 entities x 32 units), then av = ac * au ----
    if (t < SROWS) {
        int j = t, e = j & 31;
        int n = ss * 8 + (j >> 5);          // global entity
        bool m = lmask[((size_t)n * B + b) * ENT + e] != 0;
        float v = m ? -1e30f : s_sc[j];
        float mx = v;
        for (int o = 16; o >= 1; o >>= 1) mx = fmaxf(mx, __shfl_xor(mx, o));
        float p = m ? 0.f : __expf(v - mx);
        float sm = p;
        for (int o = 16; o >= 1; o >>= 1) sm += __shfl_xor(sm, o);
        float au = (sm > 0.f) ? p / sm : 0.f;
        float av = s_ac[n] * au;
        s_av[j] = av;
        int s = ss * SROWS + j;
        out_au[b * S + s] = au;
        out_av[b * S + s] = av;
    }
    __syncthreads();

    // ---- weighted context partial: half h streams rows h*128..h*128+127 ----
    int half = t >> 8, tt = t & 255;
    float4 acc = {0.f, 0.f, 0.f, 0.f};
    const float4* base =
        (const float4*)(ll + ((size_t)(ss * SROWS + half * 128) * B + b) * D) + tt;
#pragma unroll 8
    for (int j = 0; j < 128; ++j) {
        float4 x = base[(size_t)j * (B * D / 4)];
        float w = s_av[half * 128 + j];
        acc.x += w * x.x;
        acc.y += w * x.y;
        acc.z += w * x.z;
        acc.w += w * x.w;
    }
    if (half == 1) s_red[tt] = acc;
    __syncthreads();
    if (half == 0) {
        float4 o = s_red[tt];
        acc.x += o.x; acc.y += o.y; acc.z += o.z; acc.w += o.w;
        *(float4*)(pf + ((size_t)ss * B + b) * D + tt * 4) = acc;
    }
}

// grid (16, 8): x = 64-row group of W_out, y = 4-batch group.
// Fuses the slab reduction: cc context half = sum over NSLAB pf partials (L2/L3-resident).
__global__ __launch_bounds__(256) void k_out(const float* __restrict__ Wo,
                                             const float* __restrict__ src,
                                             const float* __restrict__ pf,
                                             float* __restrict__ out_h) {
    __shared__ alignas(16) float cc[4][2 * D];      // 32 KB concat for 4 batches
    __shared__ float red[4][64][4];                 // 4 KB
    int t = threadIdx.x, jg = blockIdx.x, bg = blockIdx.y;
    for (int f = t; f < 4 * (2 * D / 4); f += 256) {  // 2048 float4s
        int bb = f >> 9, part = f & 511;
        int b = bg * 4 + bb;
        float4 v;
        if (part < 256) {
            float4 a = {0.f, 0.f, 0.f, 0.f};
            const float4* pp = (const float4*)(pf + (size_t)b * D) + part;
#pragma unroll
            for (int ssi = 0; ssi < NSLAB; ++ssi) {
                float4 x = pp[(size_t)ssi * (B * D / 4)];
                a.x += x.x; a.y += x.y; a.z += x.z; a.w += x.w;
            }
            v = a;
        } else {
            v = *(const float4*)(src + (size_t)b * D + (part - 256) * 4);
        }
        *(float4*)(&cc[bb][part * 4]) = v;
    }
    __syncthreads();
    int jl = t & 63, kq = t >> 6;
    int j = jg * 64 + jl;
    const float4* wp = (const float4*)(Wo + (size_t)j * 2 * D) + kq * 128;  // 512 k
    float acc[4] = {0.f, 0.f, 0.f, 0.f};
#pragma unroll 4
    for (int i = 0; i < 128; ++i) {
        float4 w = wp[i];
        int k = kq * 512 + i * 4;
#pragma unroll
        for (int bb = 0; bb < 4; ++bb) acc[bb] += dot4(w, &cc[bb][k]);
    }
#pragma unroll
    for (int bb = 0; bb < 4; ++bb) red[kq][jl][bb] = acc[bb];
    __syncthreads();
    {
        int jl2 = t & 63, bb = t >> 6;
        float s = red[0][jl2][bb] + red[1][jl2][bb] + red[2][jl2][bb] + red[3][jl2][bb];
        out_h[(size_t)(bg * 4 + bb) * D + jg * 64 + jl2] = tanhf(s);
    }
}

extern "C" void kernel_launch(void* const* d_in, const int* in_sizes, int n_in,
                              void* d_out, int out_size, void* d_ws, size_t ws_size,
                              hipStream_t stream) {
    const float* src = (const float*)d_in[0];
    const float* hl = (const float*)d_in[1];
    const float* pe = (const float*)d_in[2];
    const float* ll = (const float*)d_in[3];
    const int* lmask = (const int*)d_in[4];
    const int* hmask = (const int*)d_in[5];
    const float* Wu = (const float*)d_in[6];
    const float* Wc = (const float*)d_in[7];
    const float* Wo = (const float*)d_in[8];

    float* out = (float*)d_out;
    float* out_h = out;                      // (B, D)
    float* out_av = out + B * D;             // (B, S)
    float* out_ac = out_av + B * S;          // (B, NENT)
    float* out_au = out_ac + B * NENT;       // (B, S)

    float* ws = (float*)d_ws;
    float* qu = ws;                          // B*UD
    float* qc = qu + B * UD;                 // B*D
    float* scb = qc + B * D;                 // B*C raw chunk scores
    float* pf = scb + B * C;                 // NSLAB*B*D slab partials (= baseline footprint)

    k_proj<<<dim3(20, 8), 256, 0, stream>>>(src, Wu, Wc, qu, qc);
    k_score<<<dim3(C, B), 256, 0, stream>>>(hl, qc, scb);
    k_fused<<<dim3(NSLAB, B), 512, 0, stream>>>(pe, ll, lmask, hmask, qu, scb,
                                                pf, out_au, out_ac, out_av);
    k_out<<<dim3(16, 8), 256, 0, stream>>>(Wo, src, pf, out_h);
}

// Round 3
// 458.877 us; speedup vs baseline: 1.0420x; 1.0063x over previous
//
#include <hip/hip_runtime.h>

#define B 32
#define D 1024
#define UD 256
#define ENT 32
#define NENT 64
#define S 2048
#define C 65
#define NSLAB 8     // 8 entities per block, one per wave (512 threads)

__device__ __forceinline__ float dot4(float4 w, const float* q) {
    return w.x * q[0] + w.y * q[1] + w.z * q[2] + w.w * q[3];
}

// grid (20, 8): x = 64-row group of [W_unit; W_chunk] (1280 rows), y = 4-batch group.
__global__ __launch_bounds__(256) void k_proj(const float* __restrict__ src,
                                              const float* __restrict__ Wu,
                                              const float* __restrict__ Wc,
                                              float* __restrict__ qu,
                                              float* __restrict__ qc) {
    __shared__ alignas(16) float s_src[4][D];       // 16 KB
    __shared__ float red[4][64][4];                 // 4 KB
    int t = threadIdx.x, rg = blockIdx.x, bg = blockIdx.y;
    for (int f = t; f < 4 * (D / 4); f += 256) {
        int bb = f >> 8, i4 = f & 255;
        float4 v = *(const float4*)(src + (size_t)(bg * 4 + bb) * D + i4 * 4);
        *(float4*)(&s_src[bb][i4 * 4]) = v;
    }
    __syncthreads();
    int jl = t & 63, kq = t >> 6;
    int gj = rg * 64 + jl;
    const float* wrow = (gj < UD) ? (Wu + (size_t)gj * D) : (Wc + (size_t)(gj - UD) * D);
    const float4* wp = (const float4*)wrow + kq * 64;   // 64 float4 = 256 k
    float acc[4] = {0.f, 0.f, 0.f, 0.f};
#pragma unroll 4
    for (int i = 0; i < 64; ++i) {
        float4 w = wp[i];
        int k = kq * 256 + i * 4;
#pragma unroll
        for (int bb = 0; bb < 4; ++bb) acc[bb] += dot4(w, &s_src[bb][k]);
    }
#pragma unroll
    for (int bb = 0; bb < 4; ++bb) red[kq][jl][bb] = acc[bb];
    __syncthreads();
    {
        int jl2 = t & 63, bb = t >> 6;
        float s = red[0][jl2][bb] + red[1][jl2][bb] + red[2][jl2][bb] + red[3][jl2][bb];
        int gj2 = rg * 64 + jl2, b = bg * 4 + bb;
        if (gj2 < UD) qu[b * UD + gj2] = s;
        else qc[b * D + (gj2 - UD)] = s;
    }
}

// grid (C, B): raw chunk score sc[b*C+c] = qc[b] . hl[c,b]  (2080 blocks, latency-friendly)
__global__ __launch_bounds__(256) void k_score(const float* __restrict__ hl,
                                               const float* __restrict__ qc,
                                               float* __restrict__ sc) {
    __shared__ float red[4];
    int c = blockIdx.x, b = blockIdx.y, t = threadIdx.x;
    const float4* hp = (const float4*)(hl + ((size_t)c * B + b) * D);
    const float4* qp = (const float4*)(qc + (size_t)b * D);
    float4 h = hp[t];
    float4 q = qp[t];
    float acc = h.x * q.x + h.y * q.y + h.z * q.z + h.w * q.w;
    for (int o = 32; o >= 1; o >>= 1) acc += __shfl_xor(acc, o);
    if ((t & 63) == 0) red[t >> 6] = acc;
    __syncthreads();
    if (t == 0) sc[b * C + c] = red[0] + red[1] + red[2] + red[3];
}

// grid (NSLAB, B), 512 threads = 8 waves. Wave w owns entity n = ss*8+w end-to-end:
// chunk softmax (in-register, redundant), pe scores (1 row = 1 KB per wave-instr),
// entity softmax (intra-wave shuffles), ll stream (4 x 1 KB per row, weight via shfl).
// Barrier-free until one final 32 KB LDS combine of the 8 entity partials -> pf slab.
__global__ __launch_bounds__(512) void k_fused(const float* __restrict__ pe,
                                               const float* __restrict__ ll,
                                               const int* __restrict__ lmask,
                                               const int* __restrict__ hmask,
                                               const float* __restrict__ qu,
                                               const float* __restrict__ sc,
                                               float* __restrict__ pf,
                                               float* __restrict__ out_au,
                                               float* __restrict__ out_ac,
                                               float* __restrict__ out_av) {
    __shared__ alignas(16) float4 s_part[NSLAB][256];   // 32 KB
    int ss = blockIdx.x, b = blockIdx.y, t = threadIdx.x;
    int w = t >> 6, l = t & 63;
    int n = ss * NSLAB + w;                 // this wave's entity (wave-uniform)

    // ---- chunk masked softmax over 65 scores, fully in-register per wave ----
    bool m1 = hmask[b * C + l] != 0;        // lane l <-> chunk l (0..63)
    float x1 = m1 ? -1e30f : sc[b * C + l];
    bool m2 = hmask[b * C + 64] != 0;       // chunk 64, wave-uniform
    float x2 = m2 ? -1e30f : sc[b * C + 64];
    float mx = x1;
    for (int o = 32; o >= 1; o >>= 1) mx = fmaxf(mx, __shfl_xor(mx, o));
    mx = fmaxf(mx, x2);
    float e1 = m1 ? 0.f : __expf(x1 - mx);
    float sm = e1;
    for (int o = 32; o >= 1; o >>= 1) sm += __shfl_xor(sm, o);
    float e2 = m2 ? 0.f : __expf(x2 - mx);
    sm += e2;                               // chunk 0 never masked -> sm > 0
    int c = n + 1;                          // this entity's chunk
    float en = (c < 64) ? __shfl(e1, c) : e2;
    float ac = en / sm;
    if (l == 0) out_ac[b * NENT + n] = ac;

    // ---- unit scores: row j read as 64 lanes x float4 = 1 KB coalesced ----
    float4 qf = ((const float4*)(qu + (size_t)b * UD))[l];
    int s0 = n * ENT;                       // first source row of this entity
    const float4* pe4 = (const float4*)pe;
    float score = 0.f;                      // lane j keeps row j's score (j < 32)
#pragma unroll 4
    for (int j = 0; j < ENT; ++j) {
        float4 v = pe4[((size_t)(s0 + j) * B + b) * (UD / 4) + l];
        float p = v.x * qf.x + v.y * qf.y + v.z * qf.z + v.w * qf.w;
        for (int o = 32; o >= 1; o >>= 1) p += __shfl_xor(p, o);
        score = (l == j) ? p : score;
    }

    // ---- entity masked softmax on lanes 0..31 (upper half mirrors harmlessly) ----
    int e = l & 31;
    bool m = lmask[((size_t)n * B + b) * ENT + e] != 0;
    float v = m ? -1e30f : score;
    float emx = v;
    for (int o = 16; o >= 1; o >>= 1) emx = fmaxf(emx, __shfl_xor(emx, o));
    float p = m ? 0.f : __expf(v - emx);
    float esm = p;
    for (int o = 16; o >= 1; o >>= 1) esm += __shfl_xor(esm, o);
    float au = (esm > 0.f) ? p / esm : 0.f; // all-masked entity -> 0
    float av = ac * au;
    if (l < ENT) {
        out_au[b * S + s0 + l] = au;
        out_av[b * S + s0 + l] = av;
    }

    // ---- stream this entity's 32 ll rows: 4 x 1 KB per row, weight via shfl ----
    float4 a0 = {0.f, 0.f, 0.f, 0.f}, a1 = a0, a2 = a0, a3 = a0;
    const float4* ll4 = (const float4*)ll;
#pragma unroll 4
    for (int j = 0; j < ENT; ++j) {
        float wv = __shfl(av, j);
        const float4* rp = ll4 + ((size_t)(s0 + j) * B + b) * (D / 4) + l;
        float4 x0 = rp[0], x1v = rp[64], x2v = rp[128], x3v = rp[192];
        a0.x += wv * x0.x;  a0.y += wv * x0.y;  a0.z += wv * x0.z;  a0.w += wv * x0.w;
        a1.x += wv * x1v.x; a1.y += wv * x1v.y; a1.z += wv * x1v.z; a1.w += wv * x1v.w;
        a2.x += wv * x2v.x; a2.y += wv * x2v.y; a2.z += wv * x2v.z; a2.w += wv * x2v.w;
        a3.x += wv * x3v.x; a3.y += wv * x3v.y; a3.z += wv * x3v.z; a3.w += wv * x3v.w;
    }
    s_part[w][l] = a0;
    s_part[w][64 + l] = a1;
    s_part[w][128 + l] = a2;
    s_part[w][192 + l] = a3;
    __syncthreads();

    // ---- combine 8 entity partials -> slab partial pf[ss][b][:] ----
    if (t < 256) {
        float4 r = {0.f, 0.f, 0.f, 0.f};
#pragma unroll
        for (int ww = 0; ww < NSLAB; ++ww) {
            float4 x = s_part[ww][t];
            r.x += x.x; r.y += x.y; r.z += x.z; r.w += x.w;
        }
        *(float4*)(pf + ((size_t)ss * B + b) * D + t * 4) = r;
    }
}

// grid (16, 8): x = 64-row group of W_out, y = 4-batch group.
// Fuses the slab reduction: cc context half = sum over NSLAB pf partials (L2/L3-resident).
__global__ __launch_bounds__(256) void k_out(const float* __restrict__ Wo,
                                             const float* __restrict__ src,
                                             const float* __restrict__ pf,
                                             float* __restrict__ out_h) {
    __shared__ alignas(16) float cc[4][2 * D];      // 32 KB concat for 4 batches
    __shared__ float red[4][64][4];                 // 4 KB
    int t = threadIdx.x, jg = blockIdx.x, bg = blockIdx.y;
    for (int f = t; f < 4 * (2 * D / 4); f += 256) {  // 2048 float4s
        int bb = f >> 9, part = f & 511;
        int b = bg * 4 + bb;
        float4 v;
        if (part < 256) {
            float4 a = {0.f, 0.f, 0.f, 0.f};
            const float4* pp = (const float4*)(pf + (size_t)b * D) + part;
#pragma unroll
            for (int ssi = 0; ssi < NSLAB; ++ssi) {
                float4 x = pp[(size_t)ssi * (B * D / 4)];
                a.x += x.x; a.y += x.y; a.z += x.z; a.w += x.w;
            }
            v = a;
        } else {
            v = *(const float4*)(src + (size_t)b * D + (part - 256) * 4);
        }
        *(float4*)(&cc[bb][part * 4]) = v;
    }
    __syncthreads();
    int jl = t & 63, kq = t >> 6;
    int j = jg * 64 + jl;
    const float4* wp = (const float4*)(Wo + (size_t)j * 2 * D) + kq * 128;  // 512 k
    float acc[4] = {0.f, 0.f, 0.f, 0.f};
#pragma unroll 4
    for (int i = 0; i < 128; ++i) {
        float4 w = wp[i];
        int k = kq * 512 + i * 4;
#pragma unroll
        for (int bb = 0; bb < 4; ++bb) acc[bb] += dot4(w, &cc[bb][k]);
    }
#pragma unroll
    for (int bb = 0; bb < 4; ++bb) red[kq][jl][bb] = acc[bb];
    __syncthreads();
    {
        int jl2 = t & 63, bb = t >> 6;
        float s = red[0][jl2][bb] + red[1][jl2][bb] + red[2][jl2][bb] + red[3][jl2][bb];
        out_h[(size_t)(bg * 4 + bb) * D + jg * 64 + jl2] = tanhf(s);
    }
}

extern "C" void kernel_launch(void* const* d_in, const int* in_sizes, int n_in,
                              void* d_out, int out_size, void* d_ws, size_t ws_size,
                              hipStream_t stream) {
    const float* src = (const float*)d_in[0];
    const float* hl = (const float*)d_in[1];
    const float* pe = (const float*)d_in[2];
    const float* ll = (const float*)d_in[3];
    const int* lmask = (const int*)d_in[4];
    const int* hmask = (const int*)d_in[5];
    const float* Wu = (const float*)d_in[6];
    const float* Wc = (const float*)d_in[7];
    const float* Wo = (const float*)d_in[8];

    float* out = (float*)d_out;
    float* out_h = out;                      // (B, D)
    float* out_av = out + B * D;             // (B, S)
    float* out_ac = out_av + B * S;          // (B, NENT)
    float* out_au = out_ac + B * NENT;       // (B, S)

    float* ws = (float*)d_ws;
    float* qu = ws;                          // B*UD
    float* qc = qu + B * UD;                 // B*D
    float* scb = qc + B * D;                 // B*C raw chunk scores
    float* pf = scb + B * C;                 // NSLAB*B*D slab partials (= baseline footprint)

    k_proj<<<dim3(20, 8), 256, 0, stream>>>(src, Wu, Wc, qu, qc);
    k_score<<<dim3(C, B), 256, 0, stream>>>(hl, qc, scb);
    k_fused<<<dim3(NSLAB, B), 512, 0, stream>>>(pe, ll, lmask, hmask, qu, scb,
                                                pf, out_au, out_ac, out_av);
    k_out<<<dim3(16, 8), 256, 0, stream>>>(Wo, src, pf, out_h);
}